// Round 15
// baseline (38.827 us; speedup 1.0000x reference)
//
#include <hip/hip_runtime.h>

// TransE 'rhs': pred[b,n] = MARGIN - ||(s+r)[b] - e[n]||_2. B=32,N=200k,D=64 fp32.
//
// R14 post-mortem: per-CU balance theory dead (768-grid no better). Plateau
// ~20us across occupancy 6-12 waves/CU and tile sizes -> suspect the ONE
// path difference vs 6+TB/s reference kernels: global_load_lds DMA delivery.
// R15 = R12 byte-for-byte (schedule, math, swizzle, clean 1KB-row stores)
// with delivery swapped to per-lane coalesced global_load_dwordx4 -> VGPR ->
// swizzled ds_write_b128 (2 reg stages, same dbuf rotation). Per-wave DS ops
// are in-order (WAR-safe); compiler emits counted vmcnt per reg dependency.

#define MARGIN 9.0f

typedef __attribute__((ext_vector_type(8)))  short bf16x8;
typedef __attribute__((ext_vector_type(16))) float f32x16;
typedef __attribute__((ext_vector_type(4)))  unsigned int u32x4;

__device__ __forceinline__ unsigned eswz(unsigned p) {   // in-row involution
    return p ^ (((p >> 8) & 15u) << 4);
}

__global__ __launch_bounds__(128)
void transe15(const float* __restrict__ s_emb,
              const float* __restrict__ rel_emb,
              const float* __restrict__ emb_e,
              float* __restrict__ out, int N)
{
    __shared__ __align__(16) char lds[32768];   // 2 waves x 2 x 8KB
    const int t = threadIdx.x, w = t >> 6, lane = t & 63;
    const int m = lane & 31, h = lane >> 5;
    char* const b0 = lds + w * 16384;
    char* const b1 = b0 + 8192;
    const int  nt32 = N >> 5;                        // 6250 tiles of 32 rows
    const long T0   = (long)blockIdx.x * 8 + w * 4;  // wave's 4 tiles

    // ---- 1. q per-lane loads first ----
    const float4* s4 = (const float4*)s_emb;
    const float4* r4 = (const float4*)rel_emb;
    float4 sv[8], rv[8];
#pragma unroll
    for (int k = 0; k < 8; ++k) sv[k] = s4[k*64 + lane];
#pragma unroll
    for (int k = 0; k < 8; ++k) rv[k] = r4[k*64 + lane];

    // ---- 2. e loads: T0 -> R0, T1 -> R1 (coalesced 1KB/instr) ----
    const float4* e4 = (const float4*)emb_e;
    auto eload = [&](long tile, float4 (&R)[8]) {
        const long ts = (tile < nt32) ? tile : (long)(nt32 - 1);
#pragma unroll
        for (int k = 0; k < 8; ++k) R[k] = e4[ts*512 + k*64 + lane];
    };
    float4 R0[8], R1[8];
    eload(T0 + 0, R0);
    eload(T0 + 1, R1);
    asm volatile("" ::: "memory");     // pin issue order: all loads in flight

    // ---- 3. q = s + r -> b0 (swizzled), hi+lo bf16 fragments ----
#pragma unroll
    for (int k = 0; k < 8; ++k) {
        const unsigned p = (unsigned)(k*1024 + lane*16);
        float4 q = make_float4(sv[k].x+rv[k].x, sv[k].y+rv[k].y,
                               sv[k].z+rv[k].z, sv[k].w+rv[k].w);
        *(float4*)(b0 + eswz(p)) = q;
    }

    const unsigned fb = (unsigned)(m*256 + h*32);
    bf16x8 qh[4], ql[4];
    float qn_part = 0.f;
#pragma unroll
    for (int tt = 0; tt < 4; ++tt) {
        const unsigned pe = eswz(fb + tt*64);
        float4 q0 = *(const float4*)(b0 + pe);
        float4 q1 = *(const float4*)(b0 + (pe ^ 16));
        const float qf[8] = {q0.x,q0.y,q0.z,q0.w, q1.x,q1.y,q1.z,q1.w};
#pragma unroll
        for (int i = 0; i < 8; ++i) {
            const float f = qf[i];
            qn_part = fmaf(f, f, qn_part);
            const unsigned u = __float_as_uint(f);
            qh[tt][i] = (short)(u >> 16);                          // trunc hi
            const float lo = f - __uint_as_float(u & 0xFFFF0000u); // exact
            ql[tt][i] = (short)(__float_as_uint(lo) >> 16);
        }
    }
    const float qn_own = qn_part + __shfl_xor(qn_part, 32);
    float qn_all[32];                      // readlane -> wave-uniform SGPRs
#pragma unroll
    for (int i = 0; i < 32; ++i)
        qn_all[i] = __uint_as_float(
            __builtin_amdgcn_readlane(__float_as_uint(qn_own), i));

    // ---- 4. staging + compute ----
    auto stage = [&](const float4 (&R)[8], char* l) {  // VGPR -> swizzled LDS
#pragma unroll
        for (int k = 0; k < 8; ++k) {
            const unsigned p = (unsigned)(k*1024 + lane*16);
            *(float4*)(l + eswz(p)) = R[k];
        }
    };

    auto compute_tile = [&](const char* L, f32x16& acc) {
#pragma unroll
        for (int i = 0; i < 16; ++i) acc[i] = 0.f;
        float en_part = 0.f;
#pragma unroll
        for (int tt = 0; tt < 4; ++tt) {
            const unsigned pe = eswz(fb + tt*64);
            float4 e0 = *(const float4*)(L + pe);
            float4 e1 = *(const float4*)(L + (pe ^ 16));
            en_part = fmaf(e0.x, e0.x, en_part);
            en_part = fmaf(e0.y, e0.y, en_part);
            en_part = fmaf(e0.z, e0.z, en_part);
            en_part = fmaf(e0.w, e0.w, en_part);
            en_part = fmaf(e1.x, e1.x, en_part);
            en_part = fmaf(e1.y, e1.y, en_part);
            en_part = fmaf(e1.z, e1.z, en_part);
            en_part = fmaf(e1.w, e1.w, en_part);
            u32x4 ep;
            ep[0] = __builtin_amdgcn_perm(__float_as_uint(e0.y),
                                          __float_as_uint(e0.x), 0x07060302u);
            ep[1] = __builtin_amdgcn_perm(__float_as_uint(e0.w),
                                          __float_as_uint(e0.z), 0x07060302u);
            ep[2] = __builtin_amdgcn_perm(__float_as_uint(e1.y),
                                          __float_as_uint(e1.x), 0x07060302u);
            ep[3] = __builtin_amdgcn_perm(__float_as_uint(e1.w),
                                          __float_as_uint(e1.z), 0x07060302u);
            const bf16x8 eh = __builtin_bit_cast(bf16x8, ep);
            acc = __builtin_amdgcn_mfma_f32_32x32x16_bf16(qh[tt], eh, acc, 0,0,0);
            acc = __builtin_amdgcn_mfma_f32_32x32x16_bf16(ql[tt], eh, acc, 0,0,0);
        }
        const float en = en_part + __shfl_xor(en_part, 32);
#pragma unroll
        for (int r = 0; r < 16; ++r) {
            const int bb = (r & 3) + 8*(r >> 2);
            const float qn_v = h ? qn_all[bb + 4] : qn_all[bb];
            const float d2 = fmaxf(fmaf(-2.f, acc[r], qn_v + en), 0.f);
            acc[r] = MARGIN - sqrtf(d2);
        }
    };

    f32x16 p0, p1, p2, p3;
    stage(R0, b0);               // waits R0's loads only (counted by compiler)
    eload(T0 + 2, R0);           // refill R0 immediately (in flight over T0,T1)
    compute_tile(b0, p0);
    stage(R1, b1);
    eload(T0 + 3, R1);
    compute_tile(b1, p1);
    stage(R0, b0);
    compute_tile(b0, p2);
    stage(R1, b1);
    compute_tile(b1, p3);

    // ---- 5. preds -> oT [32 b][256 n] (overlays e-bufs), clean store ----
    __syncthreads();                    // both waves done reading e-bufs
    float* oT = (float*)lds;
    const int nlb = w*128 + m;
#pragma unroll
    for (int r = 0; r < 16; ++r) {
        const int b = (r & 3) + 8*(r >> 2) + 4*h;
        oT[b*256 + nlb +  0] = p0[r];
        oT[b*256 + nlb + 32] = p1[r];
        oT[b*256 + nlb + 64] = p2[r];
        oT[b*256 + nlb + 96] = p3[r];
    }
    __syncthreads();

    const long nb = (long)blockIdx.x * 256;
#pragma unroll
    for (int k = 0; k < 16; ++k) {      // wave w: rows w*16..w*16+15, 1KB each
        const int  rb  = w*16 + k;
        const long col = nb + lane*4;
        if (col + 3 < N) {
            const float4 v = *(const float4*)(oT + rb*256 + lane*4);
            *(float4*)(out + (size_t)rb * N + col) = v;
        }
    }
}

extern "C" void kernel_launch(void* const* d_in, const int* in_sizes, int n_in,
                              void* d_out, int out_size, void* d_ws, size_t ws_size,
                              hipStream_t stream) {
    const float* s = (const float*)d_in[0];
    const float* r = (const float*)d_in[1];
    const float* e = (const float*)d_in[2];
    float* out = (float*)d_out;

    const int N = in_sizes[2] / 64;            // 200000
    const int grid = (N + 255) / 256;          // 782 blocks x 128 threads

    transe15<<<grid, 128, 0, stream>>>(s, r, e, out, N);
}

// Round 16
// 36.086 us; speedup vs baseline: 1.0759x; 1.0759x over previous
//
#include <hip/hip_runtime.h>

// TransE 'rhs': pred[b,n] = MARGIN - ||(s+r)[b] - e[n]||_2. B=32,N=200k,D=64 fp32.
//
// R15 post-mortem: A/B confounded -- VGPR_Count=72, compiler sank the e-loads
// (no min-waves hint), serializing HBM latency per load (0.87 TB/s). R16 =
// R15 with __launch_bounds__(128,2) (allows 256 VGPR -> staging regs stay
// live), and issue-pinning fences after each eload. Still: eswz swizzle,
// hi+lo q / hi-only e, counted implicit vmcnt via reg deps, clean 1KB-row
// stores. A/B vs R12 (DMA, 20.2us) isolates the delivery path.

#define MARGIN 9.0f

typedef __attribute__((ext_vector_type(8)))  short bf16x8;
typedef __attribute__((ext_vector_type(16))) float f32x16;
typedef __attribute__((ext_vector_type(4)))  unsigned int u32x4;

__device__ __forceinline__ unsigned eswz(unsigned p) {   // in-row involution
    return p ^ (((p >> 8) & 15u) << 4);
}

__global__ __launch_bounds__(128, 2)
void transe16(const float* __restrict__ s_emb,
              const float* __restrict__ rel_emb,
              const float* __restrict__ emb_e,
              float* __restrict__ out, int N)
{
    __shared__ __align__(16) char lds[32768];   // 2 waves x 2 x 8KB
    const int t = threadIdx.x, w = t >> 6, lane = t & 63;
    const int m = lane & 31, h = lane >> 5;
    char* const b0 = lds + w * 16384;
    char* const b1 = b0 + 8192;
    const int  nt32 = N >> 5;                        // 6250 tiles of 32 rows
    const long T0   = (long)blockIdx.x * 8 + w * 4;  // wave's 4 tiles

    // ---- 1. q per-lane loads first ----
    const float4* s4 = (const float4*)s_emb;
    const float4* r4 = (const float4*)rel_emb;
    float4 sv[8], rv[8];
#pragma unroll
    for (int k = 0; k < 8; ++k) sv[k] = s4[k*64 + lane];
#pragma unroll
    for (int k = 0; k < 8; ++k) rv[k] = r4[k*64 + lane];

    // ---- 2. e loads: T0 -> R0, T1 -> R1 (coalesced 1KB/instr) ----
    const float4* e4 = (const float4*)emb_e;
    auto eload = [&](long tile, float4 (&R)[8]) {
        const long ts = (tile < nt32) ? tile : (long)(nt32 - 1);
#pragma unroll
        for (int k = 0; k < 8; ++k) R[k] = e4[ts*512 + k*64 + lane];
    };
    float4 R0[8], R1[8];
    eload(T0 + 0, R0);
    eload(T0 + 1, R1);
    asm volatile("" ::: "memory");     // pin: all 16 e-loads + q loads issued

    // ---- 3. q = s + r -> b0 (swizzled), hi+lo bf16 fragments ----
#pragma unroll
    for (int k = 0; k < 8; ++k) {
        const unsigned p = (unsigned)(k*1024 + lane*16);
        float4 q = make_float4(sv[k].x+rv[k].x, sv[k].y+rv[k].y,
                               sv[k].z+rv[k].z, sv[k].w+rv[k].w);
        *(float4*)(b0 + eswz(p)) = q;
    }

    const unsigned fb = (unsigned)(m*256 + h*32);
    bf16x8 qh[4], ql[4];
    float qn_part = 0.f;
#pragma unroll
    for (int tt = 0; tt < 4; ++tt) {
        const unsigned pe = eswz(fb + tt*64);
        float4 q0 = *(const float4*)(b0 + pe);
        float4 q1 = *(const float4*)(b0 + (pe ^ 16));
        const float qf[8] = {q0.x,q0.y,q0.z,q0.w, q1.x,q1.y,q1.z,q1.w};
#pragma unroll
        for (int i = 0; i < 8; ++i) {
            const float f = qf[i];
            qn_part = fmaf(f, f, qn_part);
            const unsigned u = __float_as_uint(f);
            qh[tt][i] = (short)(u >> 16);                          // trunc hi
            const float lo = f - __uint_as_float(u & 0xFFFF0000u); // exact
            ql[tt][i] = (short)(__float_as_uint(lo) >> 16);
        }
    }
    const float qn_own = qn_part + __shfl_xor(qn_part, 32);
    float qn_all[32];                      // readlane -> wave-uniform SGPRs
#pragma unroll
    for (int i = 0; i < 32; ++i)
        qn_all[i] = __uint_as_float(
            __builtin_amdgcn_readlane(__float_as_uint(qn_own), i));

    // ---- 4. staging + compute ----
    auto stage = [&](const float4 (&R)[8], char* l) {  // VGPR -> swizzled LDS
#pragma unroll
        for (int k = 0; k < 8; ++k) {
            const unsigned p = (unsigned)(k*1024 + lane*16);
            *(float4*)(l + eswz(p)) = R[k];
        }
    };

    auto compute_tile = [&](const char* L, f32x16& acc) {
#pragma unroll
        for (int i = 0; i < 16; ++i) acc[i] = 0.f;
        float en_part = 0.f;
#pragma unroll
        for (int tt = 0; tt < 4; ++tt) {
            const unsigned pe = eswz(fb + tt*64);
            float4 e0 = *(const float4*)(L + pe);
            float4 e1 = *(const float4*)(L + (pe ^ 16));
            en_part = fmaf(e0.x, e0.x, en_part);
            en_part = fmaf(e0.y, e0.y, en_part);
            en_part = fmaf(e0.z, e0.z, en_part);
            en_part = fmaf(e0.w, e0.w, en_part);
            en_part = fmaf(e1.x, e1.x, en_part);
            en_part = fmaf(e1.y, e1.y, en_part);
            en_part = fmaf(e1.z, e1.z, en_part);
            en_part = fmaf(e1.w, e1.w, en_part);
            u32x4 ep;
            ep[0] = __builtin_amdgcn_perm(__float_as_uint(e0.y),
                                          __float_as_uint(e0.x), 0x07060302u);
            ep[1] = __builtin_amdgcn_perm(__float_as_uint(e0.w),
                                          __float_as_uint(e0.z), 0x07060302u);
            ep[2] = __builtin_amdgcn_perm(__float_as_uint(e1.y),
                                          __float_as_uint(e1.x), 0x07060302u);
            ep[3] = __builtin_amdgcn_perm(__float_as_uint(e1.w),
                                          __float_as_uint(e1.z), 0x07060302u);
            const bf16x8 eh = __builtin_bit_cast(bf16x8, ep);
            acc = __builtin_amdgcn_mfma_f32_32x32x16_bf16(qh[tt], eh, acc, 0,0,0);
            acc = __builtin_amdgcn_mfma_f32_32x32x16_bf16(ql[tt], eh, acc, 0,0,0);
        }
        const float en = en_part + __shfl_xor(en_part, 32);
#pragma unroll
        for (int r = 0; r < 16; ++r) {
            const int bb = (r & 3) + 8*(r >> 2);
            const float qn_v = h ? qn_all[bb + 4] : qn_all[bb];
            const float d2 = fmaxf(fmaf(-2.f, acc[r], qn_v + en), 0.f);
            acc[r] = MARGIN - sqrtf(d2);
        }
    };

    f32x16 p0, p1, p2, p3;
    stage(R0, b0);               // compiler waits R0's loads only (reg dep)
    eload(T0 + 2, R0);           // refill R0: in flight across 2 computes
    asm volatile("" ::: "memory");
    compute_tile(b0, p0);
    stage(R1, b1);
    eload(T0 + 3, R1);
    asm volatile("" ::: "memory");
    compute_tile(b1, p1);
    stage(R0, b0);
    compute_tile(b0, p2);
    stage(R1, b1);
    compute_tile(b1, p3);

    // ---- 5. preds -> oT [32 b][256 n] (overlays e-bufs), clean store ----
    __syncthreads();                    // both waves done reading e-bufs
    float* oT = (float*)lds;
    const int nlb = w*128 + m;
#pragma unroll
    for (int r = 0; r < 16; ++r) {
        const int b = (r & 3) + 8*(r >> 2) + 4*h;
        oT[b*256 + nlb +  0] = p0[r];
        oT[b*256 + nlb + 32] = p1[r];
        oT[b*256 + nlb + 64] = p2[r];
        oT[b*256 + nlb + 96] = p3[r];
    }
    __syncthreads();

    const long nb = (long)blockIdx.x * 256;
#pragma unroll
    for (int k = 0; k < 16; ++k) {      // wave w: rows w*16..w*16+15, 1KB each
        const int  rb  = w*16 + k;
        const long col = nb + lane*4;
        if (col + 3 < N) {
            const float4 v = *(const float4*)(oT + rb*256 + lane*4);
            *(float4*)(out + (size_t)rb * N + col) = v;
        }
    }
}

extern "C" void kernel_launch(void* const* d_in, const int* in_sizes, int n_in,
                              void* d_out, int out_size, void* d_ws, size_t ws_size,
                              hipStream_t stream) {
    const float* s = (const float*)d_in[0];
    const float* r = (const float*)d_in[1];
    const float* e = (const float*)d_in[2];
    float* out = (float*)d_out;

    const int N = in_sizes[2] / 64;            // 200000
    const int grid = (N + 255) / 256;          // 782 blocks x 128 threads

    transe16<<<grid, 128, 0, stream>>>(s, r, e, out, N);
}

// Round 17
// 22.241 us; speedup vs baseline: 1.7457x; 1.6225x over previous
//
#include <hip/hip_runtime.h>

// TransE 'rhs': pred[b,n] = MARGIN - ||(s+r)[b] - e[n]||_2. B=32,N=200k,D=64 fp32.
//
// R16 post-mortem: compiler sank reg-staged loads AGAIN (VGPR=92) -> A/B still
// confounded. R17: force the reg path with inline-asm global_load_dwordx4
// into named "=&v" float4 regs (cannot be sunk/killed) + fully manual counted
// vmcnt ledger (all vmem is asm or DMA, compiler emits none until the final
// stores). Structure/math/stores byte-identical to R12 (20.2us DMA baseline):
// eswz both-side swizzle, hi+lo q / hi-only e, 8 MFMA/tile, preds in regs,
// oT overlay, clean 1KB-row stores, grid 782 x 128.
// vmcnt ledger: issue qDMA(16), E0(8), E1(8) -> wait16 (q done) -> frag build
// -> wait8 (E0) -> stage E0, reload T2->E0 -> compute -> wait8 (E1) -> stage,
// reload T3->E1 -> compute -> wait8 (T2) -> stage, compute -> wait0 -> stage,
// compute. Outstanding never <8 mid-loop.

#define MARGIN 9.0f

typedef __attribute__((ext_vector_type(8)))  short bf16x8;
typedef __attribute__((ext_vector_type(16))) float f32x16;
typedef __attribute__((ext_vector_type(4)))  unsigned int u32x4;

typedef __attribute__((address_space(3))) void        lds_vp;
typedef __attribute__((address_space(1))) const void  glb_vp;

__device__ __forceinline__ unsigned eswz(unsigned p) {   // in-row involution
    return p ^ (((p >> 8) & 15u) << 4);
}

#define VMWAIT(n) do { \
    asm volatile("s_waitcnt vmcnt(" #n ")" ::: "memory"); \
    __builtin_amdgcn_sched_barrier(0); } while (0)

__global__ __launch_bounds__(128, 2)
void transe17(const float* __restrict__ s_emb,
              const float* __restrict__ rel_emb,
              const float* __restrict__ emb_e,
              float* __restrict__ out, int N)
{
    __shared__ __align__(16) char lds[32768];   // 2 waves x 2 x 8KB
    const int t = threadIdx.x, w = t >> 6, lane = t & 63;
    const int m = lane & 31, h = lane >> 5;
    char* const b0 = lds + w * 16384;
    char* const b1 = b0 + 8192;
    const int  nt32 = N >> 5;                        // 6250 tiles of 32 rows
    const long T0   = (long)blockIdx.x * 8 + w * 4;  // wave's 4 tiles

    // ---- 1. q via DMA: s->b0, r->b1 (16 DMA instrs, oldest in FIFO) ----
    auto dma8g = [&](const char* g, char* l) {
#pragma unroll
        for (int k = 0; k < 8; ++k) {
            const unsigned p = (unsigned)(k*1024 + lane*16);
            __builtin_amdgcn_global_load_lds((glb_vp*)(g + eswz(p)),
                                             (lds_vp*)(l + k*1024), 16, 0, 0);
        }
    };
    dma8g((const char*)s_emb,   b0);
    dma8g((const char*)rel_emb, b1);
    __builtin_amdgcn_sched_barrier(0);

    // ---- 2. e-tile asm loads into forced-live registers ----
    float4 E0[8], E1[8];
    auto eload = [&](long tile, float4 (&E)[8]) {    // 8 x 1KB coalesced
        const long ts = (tile < nt32) ? tile : (long)(nt32 - 1);
        const char* g = (const char*)emb_e + ts * 8192 + (unsigned)(lane * 16);
#pragma unroll
        for (int k = 0; k < 8; ++k) {
            asm volatile("global_load_dwordx4 %0, %1, off"
                         : "=&v"(E[k]) : "v"(g + k*1024) : "memory");
        }
    };
    eload(T0 + 0, E0);                               // vmcnt: 24
    eload(T0 + 1, E1);                               // vmcnt: 32

    // ---- 3. q fragments (hi + exact-residual bf16) + qnorm ----
    VMWAIT(16);                                      // q DMAs done (16 newer)
    const unsigned fb = (unsigned)(m*256 + h*32);
    bf16x8 qh[4], ql[4];
    float qn_part = 0.f;
#pragma unroll
    for (int tt = 0; tt < 4; ++tt) {
        const unsigned pe = eswz(fb + tt*64);
        float4 s0 = *(const float4*)(b0 + pe);
        float4 s1 = *(const float4*)(b0 + (pe ^ 16));
        float4 r0 = *(const float4*)(b1 + pe);
        float4 r1 = *(const float4*)(b1 + (pe ^ 16));
        const float qf[8] = { s0.x+r0.x, s0.y+r0.y, s0.z+r0.z, s0.w+r0.w,
                              s1.x+r1.x, s1.y+r1.y, s1.z+r1.z, s1.w+r1.w };
#pragma unroll
        for (int i = 0; i < 8; ++i) {
            const float f = qf[i];
            qn_part = fmaf(f, f, qn_part);
            const unsigned u = __float_as_uint(f);
            qh[tt][i] = (short)(u >> 16);                          // trunc hi
            const float lo = f - __uint_as_float(u & 0xFFFF0000u); // exact
            ql[tt][i] = (short)(__float_as_uint(lo) >> 16);
        }
    }
    const float qn_own = qn_part + __shfl_xor(qn_part, 32);
    float qn_all[32];                      // readlane -> wave-uniform SGPRs
#pragma unroll
    for (int i = 0; i < 32; ++i)
        qn_all[i] = __uint_as_float(
            __builtin_amdgcn_readlane(__float_as_uint(qn_own), i));
    asm volatile("s_waitcnt lgkmcnt(0)" ::: "memory");  // frag reads retired
    __builtin_amdgcn_sched_barrier(0);

    // ---- 4. stage / compute helpers ----
    auto stage = [&](const float4 (&E)[8], char* l) {   // regs -> swizzled LDS
#pragma unroll
        for (int k = 0; k < 8; ++k) {
            const unsigned p = (unsigned)(k*1024 + lane*16);
            *(float4*)(l + eswz(p)) = E[k];
        }
    };

    auto compute_tile = [&](const char* L, f32x16& acc) {
#pragma unroll
        for (int i = 0; i < 16; ++i) acc[i] = 0.f;
        float en_part = 0.f;
#pragma unroll
        for (int tt = 0; tt < 4; ++tt) {
            const unsigned pe = eswz(fb + tt*64);
            float4 e0 = *(const float4*)(L + pe);
            float4 e1 = *(const float4*)(L + (pe ^ 16));
            en_part = fmaf(e0.x, e0.x, en_part);
            en_part = fmaf(e0.y, e0.y, en_part);
            en_part = fmaf(e0.z, e0.z, en_part);
            en_part = fmaf(e0.w, e0.w, en_part);
            en_part = fmaf(e1.x, e1.x, en_part);
            en_part = fmaf(e1.y, e1.y, en_part);
            en_part = fmaf(e1.z, e1.z, en_part);
            en_part = fmaf(e1.w, e1.w, en_part);
            u32x4 ep;
            ep[0] = __builtin_amdgcn_perm(__float_as_uint(e0.y),
                                          __float_as_uint(e0.x), 0x07060302u);
            ep[1] = __builtin_amdgcn_perm(__float_as_uint(e0.w),
                                          __float_as_uint(e0.z), 0x07060302u);
            ep[2] = __builtin_amdgcn_perm(__float_as_uint(e1.y),
                                          __float_as_uint(e1.x), 0x07060302u);
            ep[3] = __builtin_amdgcn_perm(__float_as_uint(e1.w),
                                          __float_as_uint(e1.z), 0x07060302u);
            const bf16x8 eh = __builtin_bit_cast(bf16x8, ep);
            acc = __builtin_amdgcn_mfma_f32_32x32x16_bf16(qh[tt], eh, acc, 0,0,0);
            acc = __builtin_amdgcn_mfma_f32_32x32x16_bf16(ql[tt], eh, acc, 0,0,0);
        }
        const float en = en_part + __shfl_xor(en_part, 32);
#pragma unroll
        for (int r = 0; r < 16; ++r) {
            const int bb = (r & 3) + 8*(r >> 2);
            const float qn_v = h ? qn_all[bb + 4] : qn_all[bb];
            const float d2 = fmaxf(fmaf(-2.f, acc[r], qn_v + en), 0.f);
            acc[r] = MARGIN - sqrtf(d2);
        }
    };

    // ---- 5. pipelined 4-tile loop, counted vmcnt (ledger in header) ----
    f32x16 p0, p1, p2, p3;
    VMWAIT(8);                   // E0 data arrived (E1's 8 still flying)
    stage(E0, b0);               // ds_write consumes regs at issue
    eload(T0 + 2, E0);           // vmcnt: 8(E1) + 8(T2) = 16
    compute_tile(b0, p0);
    VMWAIT(8);                   // E1 arrived (T2 flying)
    stage(E1, b1);
    eload(T0 + 3, E1);           // vmcnt: 8(T2) + 8(T3) = 16
    compute_tile(b1, p1);
    VMWAIT(8);                   // T2 arrived (T3 flying)
    stage(E0, b0);
    compute_tile(b0, p2);
    VMWAIT(0);                   // T3 arrived
    stage(E1, b1);
    compute_tile(b1, p3);

    // ---- 6. preds -> oT [32 b][256 n] (overlays e-bufs), clean store ----
    __syncthreads();                    // both waves done reading e-bufs
    float* oT = (float*)lds;
    const int nlb = w*128 + m;
#pragma unroll
    for (int r = 0; r < 16; ++r) {
        const int b = (r & 3) + 8*(r >> 2) + 4*h;
        oT[b*256 + nlb +  0] = p0[r];
        oT[b*256 + nlb + 32] = p1[r];
        oT[b*256 + nlb + 64] = p2[r];
        oT[b*256 + nlb + 96] = p3[r];
    }
    __syncthreads();

    const long nb = (long)blockIdx.x * 256;
#pragma unroll
    for (int k = 0; k < 16; ++k) {      // wave w: rows w*16..w*16+15, 1KB each
        const int  rb  = w*16 + k;
        const long col = nb + lane*4;
        if (col + 3 < N) {
            const float4 v = *(const float4*)(oT + rb*256 + lane*4);
            *(float4*)(out + (size_t)rb * N + col) = v;
        }
    }
}

extern "C" void kernel_launch(void* const* d_in, const int* in_sizes, int n_in,
                              void* d_out, int out_size, void* d_ws, size_t ws_size,
                              hipStream_t stream) {
    const float* s = (const float*)d_in[0];
    const float* r = (const float*)d_in[1];
    const float* e = (const float*)d_in[2];
    float* out = (float*)d_out;

    const int N = in_sizes[2] / 64;            // 200000
    const int grid = (N + 255) / 256;          // 782 blocks x 128 threads

    transe17<<<grid, 128, 0, stream>>>(s, r, e, out, N);
}

// Round 18
// 20.214 us; speedup vs baseline: 1.9208x; 1.1003x over previous
//
#include <hip/hip_runtime.h>

// TransE 'rhs': pred[b,n] = MARGIN - ||(s+r)[b] - e[n]||_2. B=32,N=200k,D=64 fp32.
//
// R17 post-mortem: forced reg-path (manual vmcnt, live regs) TIES DMA
// (22.2 vs 20.2us) -> delivery mechanism exonerated. Plateau ~20us robust
// across occupancy/tile/path/depth. Little's law: implied latency >4us at
// the nominal outstanding bytes -> real outstanding is capped well below
// issue, i.e. a per-CU miss-tracking cap (L1/TCP MSHR). R18 = R12 verbatim
// with ONE bit changed: e-tile DMAs carry aux=1 (SC0 = L1-bypass, L2-direct)
// to take the L1 miss queue out of the e-stream path while preserving L2/L3
// allocation (keeps e's inter-replay L3 residency, FETCH ~25MB).

#define MARGIN 9.0f

typedef __attribute__((ext_vector_type(8)))  short bf16x8;
typedef __attribute__((ext_vector_type(16))) float f32x16;
typedef __attribute__((ext_vector_type(4)))  unsigned int u32x4;

typedef __attribute__((address_space(3))) void        lds_vp;
typedef __attribute__((address_space(1))) const void  glb_vp;

__device__ __forceinline__ unsigned eswz(unsigned p) {   // in-row involution
    return p ^ (((p >> 8) & 15u) << 4);
}

__global__ __launch_bounds__(128, 3)
void transe18(const float* __restrict__ s_emb,
              const float* __restrict__ rel_emb,
              const float* __restrict__ emb_e,
              float* __restrict__ out, int N)
{
    __shared__ __align__(16) char lds[32768];   // 2 waves x 2 x 8KB
    const int t = threadIdx.x, w = t >> 6, lane = t & 63;
    const int m = lane & 31, h = lane >> 5;
    char* const b0 = lds + w * 16384;
    char* const b1 = b0 + 8192;
    const int  nt32 = N >> 5;                        // 6250 tiles of 32 rows
    const long T0   = (long)blockIdx.x * 8 + w * 4;  // wave's 4 tiles

    // ---- 1. q per-lane loads first (oldest in vmcnt FIFO) ----
    const float4* s4 = (const float4*)s_emb;
    const float4* r4 = (const float4*)rel_emb;
    float4 sv[8], rv[8];
#pragma unroll
    for (int k = 0; k < 8; ++k) sv[k] = s4[k*64 + lane];
#pragma unroll
    for (int k = 0; k < 8; ++k) rv[k] = r4[k*64 + lane];

    auto dma8 = [&](long tile, char* l) {   // 8 x 1KB DMA, SC0 = L1-bypass
        const long ts = (tile < nt32) ? tile : (long)(nt32 - 1);
        const char* g = (const char*)emb_e + ts * 8192;
#pragma unroll
        for (int k = 0; k < 8; ++k) {
            const unsigned p = (unsigned)(k*1024 + lane*16);
            __builtin_amdgcn_global_load_lds((glb_vp*)(g + eswz(p)),
                                             (lds_vp*)(l + k*1024), 16, 0, 1);
        }
    };

    // ---- 2. e-DMA for tile T1 -> b1 (in flight during q work) ----
    dma8(T0 + 1, b1);

    // ---- 3. q = s + r -> b0 (swizzled), hi+lo bf16 fragments ----
#pragma unroll
    for (int k = 0; k < 8; ++k) {
        const unsigned p = (unsigned)(k*1024 + lane*16);
        float4 q = make_float4(sv[k].x+rv[k].x, sv[k].y+rv[k].y,
                               sv[k].z+rv[k].z, sv[k].w+rv[k].w);
        *(float4*)(b0 + eswz(p)) = q;
    }
    asm volatile("s_waitcnt lgkmcnt(0)" ::: "memory");

    const unsigned fb = (unsigned)(m*256 + h*32);
    bf16x8 qh[4], ql[4];
    float qn_part = 0.f;
#pragma unroll
    for (int tt = 0; tt < 4; ++tt) {
        const unsigned pe = eswz(fb + tt*64);
        float4 q0 = *(const float4*)(b0 + pe);
        float4 q1 = *(const float4*)(b0 + (pe ^ 16));
        const float qf[8] = {q0.x,q0.y,q0.z,q0.w, q1.x,q1.y,q1.z,q1.w};
#pragma unroll
        for (int i = 0; i < 8; ++i) {
            const float f = qf[i];
            qn_part = fmaf(f, f, qn_part);
            const unsigned u = __float_as_uint(f);
            qh[tt][i] = (short)(u >> 16);                          // trunc hi
            const float lo = f - __uint_as_float(u & 0xFFFF0000u); // exact
            ql[tt][i] = (short)(__float_as_uint(lo) >> 16);
        }
    }
    const float qn_own = qn_part + __shfl_xor(qn_part, 32);
    float qn_all[32];                      // readlane -> wave-uniform SGPRs
#pragma unroll
    for (int i = 0; i < 32; ++i)
        qn_all[i] = __uint_as_float(
            __builtin_amdgcn_readlane(__float_as_uint(qn_own), i));

    asm volatile("s_waitcnt lgkmcnt(0)" ::: "memory");  // q frag reads done
    dma8(T0 + 0, b0);                                   // FIFO: T1(8), T0(8)

    // ---- 4. compute (preds overwrite acc in place) ----
    auto compute_tile = [&](const char* L, f32x16& acc) {
#pragma unroll
        for (int i = 0; i < 16; ++i) acc[i] = 0.f;
        float en_part = 0.f;
#pragma unroll
        for (int tt = 0; tt < 4; ++tt) {
            const unsigned pe = eswz(fb + tt*64);
            float4 e0 = *(const float4*)(L + pe);
            float4 e1 = *(const float4*)(L + (pe ^ 16));
            en_part = fmaf(e0.x, e0.x, en_part);
            en_part = fmaf(e0.y, e0.y, en_part);
            en_part = fmaf(e0.z, e0.z, en_part);
            en_part = fmaf(e0.w, e0.w, en_part);
            en_part = fmaf(e1.x, e1.x, en_part);
            en_part = fmaf(e1.y, e1.y, en_part);
            en_part = fmaf(e1.z, e1.z, en_part);
            en_part = fmaf(e1.w, e1.w, en_part);
            u32x4 ep;
            ep[0] = __builtin_amdgcn_perm(__float_as_uint(e0.y),
                                          __float_as_uint(e0.x), 0x07060302u);
            ep[1] = __builtin_amdgcn_perm(__float_as_uint(e0.w),
                                          __float_as_uint(e0.z), 0x07060302u);
            ep[2] = __builtin_amdgcn_perm(__float_as_uint(e1.y),
                                          __float_as_uint(e1.x), 0x07060302u);
            ep[3] = __builtin_amdgcn_perm(__float_as_uint(e1.w),
                                          __float_as_uint(e1.z), 0x07060302u);
            const bf16x8 eh = __builtin_bit_cast(bf16x8, ep);
            acc = __builtin_amdgcn_mfma_f32_32x32x16_bf16(qh[tt], eh, acc, 0,0,0);
            acc = __builtin_amdgcn_mfma_f32_32x32x16_bf16(ql[tt], eh, acc, 0,0,0);
        }
        const float en = en_part + __shfl_xor(en_part, 32);
#pragma unroll
        for (int r = 0; r < 16; ++r) {
            const int bb = (r & 3) + 8*(r >> 2);
            const float qn_v = h ? qn_all[bb + 4] : qn_all[bb];
            const float d2 = fmaxf(fmaf(-2.f, acc[r], qn_v + en), 0.f);
            acc[r] = MARGIN - sqrtf(d2);
        }
    };

    f32x16 p0, p1, p2, p3;
    asm volatile("s_waitcnt vmcnt(8)" ::: "memory");    // T1 done, T0 flying
    compute_tile(b1, p1);
    asm volatile("s_waitcnt lgkmcnt(0)" ::: "memory");  // b1 reads retired
    dma8(T0 + 2, b1);                                   // FIFO: T0, T2
    asm volatile("s_waitcnt vmcnt(8)" ::: "memory");    // T0 done, T2 flying
    compute_tile(b0, p0);
    asm volatile("s_waitcnt lgkmcnt(0)" ::: "memory");  // b0 reads retired
    dma8(T0 + 3, b0);                                   // FIFO: T2, T3
    asm volatile("s_waitcnt vmcnt(8)" ::: "memory");    // T2 done, T3 flying
    compute_tile(b1, p2);
    asm volatile("s_waitcnt vmcnt(0)" ::: "memory");    // T3 done
    compute_tile(b0, p3);

    // ---- 5. preds -> oT [32 b][256 n] (overlays e-bufs), clean store ----
    __syncthreads();                    // both waves done reading e-bufs
    float* oT = (float*)lds;
    const int nlb = w*128 + m;
#pragma unroll
    for (int r = 0; r < 16; ++r) {
        const int b = (r & 3) + 8*(r >> 2) + 4*h;
        oT[b*256 + nlb +  0] = p0[r];
        oT[b*256 + nlb + 32] = p1[r];
        oT[b*256 + nlb + 64] = p2[r];
        oT[b*256 + nlb + 96] = p3[r];
    }
    __syncthreads();

    const long nb = (long)blockIdx.x * 256;
#pragma unroll
    for (int k = 0; k < 16; ++k) {      // wave w: rows w*16..w*16+15, 1KB each
        const int  rb  = w*16 + k;
        const long col = nb + lane*4;
        if (col + 3 < N) {
            const float4 v = *(const float4*)(oT + rb*256 + lane*4);
            *(float4*)(out + (size_t)rb * N + col) = v;
        }
    }
}

extern "C" void kernel_launch(void* const* d_in, const int* in_sizes, int n_in,
                              void* d_out, int out_size, void* d_ws, size_t ws_size,
                              hipStream_t stream) {
    const float* s = (const float*)d_in[0];
    const float* r = (const float*)d_in[1];
    const float* e = (const float*)d_in[2];
    float* out = (float*)d_out;

    const int N = in_sizes[2] / 64;            // 200000
    const int grid = (N + 255) / 256;          // 782 blocks x 128 threads

    transe18<<<grid, 128, 0, stream>>>(s, r, e, out, N);
}